// Round 3
// baseline (417.517 us; speedup 1.0000x reference)
//
#include <hip/hip_runtime.h>
#include <hip/hip_bf16.h>
#include <math.h>

typedef __bf16 bf16_t;
typedef __bf16 bf16x8 __attribute__((ext_vector_type(8)));
typedef float floatx4 __attribute__((ext_vector_type(4)));

#define NSEQ 3072
#define QKVLD 3072   // row stride of qkv buffer (3*16*64)
#define DMODEL 1024

// load 8 contiguous elements as bf16x8, converting if source is f32
__device__ inline bf16x8 load8(const bf16_t* p) { return *(const bf16x8*)p; }
__device__ inline bf16x8 load8(const float* p) {
    floatx4 a = *(const floatx4*)p;
    floatx4 b = *(const floatx4*)(p + 4);
    bf16x8 r;
    r[0] = (bf16_t)a[0]; r[1] = (bf16_t)a[1]; r[2] = (bf16_t)a[2]; r[3] = (bf16_t)a[3];
    r[4] = (bf16_t)b[0]; r[5] = (bf16_t)b[1]; r[6] = (bf16_t)b[2]; r[7] = (bf16_t)b[3];
    return r;
}

// ---------------------------------------------------------------------------
// Transpose+convert: in[K][N] f32 (row-major) -> out[N][K] bf16.
// grid (N/64, K/64), block 256.
// ---------------------------------------------------------------------------
__global__ __launch_bounds__(256) void transpose_k(const float* __restrict__ in,
                                                   bf16_t* __restrict__ out,
                                                   int K, int N) {
    __shared__ float T[64][65];
    const int n0 = blockIdx.x * 64, k0 = blockIdx.y * 64;
    const int tid = threadIdx.x;
    const int r = tid >> 2, c0 = (tid & 3) * 16;
#pragma unroll
    for (int i = 0; i < 4; ++i) {
        floatx4 v = *(const floatx4*)(in + (size_t)(k0 + r) * N + n0 + c0 + i * 4);
        T[r][c0 + i * 4 + 0] = v[0];
        T[r][c0 + i * 4 + 1] = v[1];
        T[r][c0 + i * 4 + 2] = v[2];
        T[r][c0 + i * 4 + 3] = v[3];
    }
    __syncthreads();
    bf16x8 o0, o1;
#pragma unroll
    for (int i = 0; i < 8; ++i) {
        o0[i] = (bf16_t)T[c0 + i][r];
        o1[i] = (bf16_t)T[c0 + 8 + i][r];
    }
    *(bf16x8*)(out + (size_t)(n0 + r) * K + k0 + c0)     = o0;
    *(bf16x8*)(out + (size_t)(n0 + r) * K + k0 + c0 + 8) = o1;
}

// ---------------------------------------------------------------------------
// GEMM: C[M][N] = A[M][K] @ BT[N][K]^T + bias. 128x128 tile, BK=64, 4 waves.
// A: f32 (converted during staging) or bf16. C: bf16 or f32.
// grid (N/128, M/128), block 256.
// ---------------------------------------------------------------------------
template <typename AT, typename CT>
__global__ __launch_bounds__(256) void gemm_bt(const AT* __restrict__ A,
                                               const bf16_t* __restrict__ BT,
                                               const float* __restrict__ bias,
                                               CT* __restrict__ C,
                                               int M, int N, int K) {
    __shared__ __attribute__((aligned(16))) bf16_t As[128][72];
    __shared__ __attribute__((aligned(16))) bf16_t Bs[128][72];
    const int tid = threadIdx.x;
    const int wave = tid >> 6, lane = tid & 63;
    const int lr = lane & 15, quad = lane >> 4;
    const int wr = (wave >> 1) * 64, wc = (wave & 1) * 64;
    const int m0 = blockIdx.y * 128, n0 = blockIdx.x * 128;

    const floatx4 fzero = {0.f, 0.f, 0.f, 0.f};
    floatx4 acc[4][4];
#pragma unroll
    for (int mi = 0; mi < 4; ++mi)
#pragma unroll
        for (int ni = 0; ni < 4; ++ni) acc[mi][ni] = fzero;

    for (int kb = 0; kb < K; kb += 64) {
        __syncthreads();
        int idx = tid;
#pragma unroll
        for (int it = 0; it < 4; ++it, idx += 256) {
            int row = idx >> 3, dc = (idx & 7) * 8;
            *(bf16x8*)&As[row][dc] = load8(A + (size_t)(m0 + row) * K + kb + dc);
            *(bf16x8*)&Bs[row][dc] = load8(BT + (size_t)(n0 + row) * K + kb + dc);
        }
        __syncthreads();
#pragma unroll
        for (int ch = 0; ch < 2; ++ch) {
            bf16x8 af[4], bfr[4];
#pragma unroll
            for (int mi = 0; mi < 4; ++mi)
                af[mi] = *(const bf16x8*)(&As[wr + mi * 16 + lr][ch * 32 + quad * 8]);
#pragma unroll
            for (int ni = 0; ni < 4; ++ni)
                bfr[ni] = *(const bf16x8*)(&Bs[wc + ni * 16 + lr][ch * 32 + quad * 8]);
#pragma unroll
            for (int mi = 0; mi < 4; ++mi)
#pragma unroll
                for (int ni = 0; ni < 4; ++ni)
                    acc[mi][ni] = __builtin_amdgcn_mfma_f32_16x16x32_bf16(af[mi], bfr[ni], acc[mi][ni], 0, 0, 0);
        }
    }

#pragma unroll
    for (int mi = 0; mi < 4; ++mi)
#pragma unroll
        for (int ni = 0; ni < 4; ++ni) {
            int n = n0 + wc + ni * 16 + lr;
            float bv = bias ? bias[n] : 0.f;
#pragma unroll
            for (int r = 0; r < 4; ++r) {
                int m = m0 + wr + mi * 16 + quad * 4 + r;
                C[(size_t)m * N + n] = (CT)(acc[mi][ni][r] + bv);
            }
        }
}

// ---------------------------------------------------------------------------
// Spiky MLP: s[h][j] = sigmoid(relu(k_j @ W1 + b1) @ W2 + b2). grid (12,16).
// ---------------------------------------------------------------------------
__global__ __launch_bounds__(256) void spiky_s(const bf16_t* __restrict__ qkv,
                                               const float* __restrict__ W1,
                                               const float* __restrict__ b1,
                                               const float* __restrict__ W2,
                                               const float* __restrict__ b2,
                                               float* __restrict__ sfull) {
    __shared__ float W1s[64][65];
    __shared__ float W2s[64], b1s[64];
    const int h = blockIdx.y;
    const int tid = threadIdx.x;
    const int j = blockIdx.x * 256 + tid;
    for (int i = tid; i < 4096; i += 256) W1s[i >> 6][i & 63] = W1[i];
    if (tid < 64) { W2s[tid] = W2[tid]; b1s[tid] = b1[tid]; }
    __syncthreads();
    float kv[64];
    const bf16x8* kp8 = (const bf16x8*)(qkv + (size_t)j * QKVLD + DMODEL + h * 64);
#pragma unroll
    for (int c = 0; c < 8; ++c) {
        bf16x8 v = kp8[c];
#pragma unroll
        for (int ii = 0; ii < 8; ++ii) kv[c * 8 + ii] = (float)v[ii];
    }
    float s = b2[0];
    for (int dd = 0; dd < 64; ++dd) {
        float a = b1s[dd];
#pragma unroll
        for (int d = 0; d < 64; ++d) a += kv[d] * W1s[d][dd];
        a = fmaxf(a, 0.f);
        s += a * W2s[dd];
    }
    s = 1.f / (1.f + __expf(-s));
    sfull[h * NSEQ + j] = s;
}

// Per-head softmax over n. grid 16, block 256.
__global__ __launch_bounds__(256) void spiky_softmax(const float* __restrict__ sfull,
                                                     float* __restrict__ sw) {
    const int h = blockIdx.x, tid = threadIdx.x;
    __shared__ float red[256];
    float mx = -1e30f;
    for (int j = tid; j < NSEQ; j += 256) mx = fmaxf(mx, sfull[h * NSEQ + j]);
    red[tid] = mx;
    __syncthreads();
    for (int s = 128; s > 0; s >>= 1) {
        if (tid < s) red[tid] = fmaxf(red[tid], red[tid + s]);
        __syncthreads();
    }
    mx = red[0];
    __syncthreads();
    float sum = 0.f;
    for (int j = tid; j < NSEQ; j += 256) sum += __expf(sfull[h * NSEQ + j] - mx);
    red[tid] = sum;
    __syncthreads();
    for (int s = 128; s > 0; s >>= 1) {
        if (tid < s) red[tid] += red[tid + s];
        __syncthreads();
    }
    float inv = 1.f / red[0];
    for (int j = tid; j < NSEQ; j += 256) sw[h * NSEQ + j] = __expf(sfull[h * NSEQ + j] - mx) * inv;
}

// ---------------------------------------------------------------------------
// Flash attention with per-query logit scale c_i = sw[h][i] * SCALE.
// grid (48, 16): x = q-tile (64 rows), y = head. block 256 (4 waves x 16 rows).
// ---------------------------------------------------------------------------
__global__ __launch_bounds__(256) void attn_kernel(const bf16_t* __restrict__ qkv,
                                                   const float* __restrict__ sw,
                                                   bf16_t* __restrict__ attn_out) {
    __shared__ __attribute__((aligned(16))) bf16_t Kt[64][72];
    __shared__ __attribute__((aligned(16))) bf16_t VT[64][72];
    __shared__ __attribute__((aligned(16))) bf16_t Pw[4][16][72];

    const int h = blockIdx.y;
    const int q0 = blockIdx.x * 64;
    const int tid = threadIdx.x;
    const int wave = tid >> 6, lane = tid & 63;
    const int lr = lane & 15, quad = lane >> 4;

    const int qrow = q0 + wave * 16 + lr;
    const bf16_t* qptr = qkv + (size_t)qrow * QKVLD + h * 64;
    bf16x8 qf0 = *(const bf16x8*)(qptr + quad * 8);
    bf16x8 qf1 = *(const bf16x8*)(qptr + 32 + quad * 8);

    float c_r[4], m_r[4], l_r[4];
#pragma unroll
    for (int r = 0; r < 4; ++r) {
        int row = q0 + wave * 16 + quad * 4 + r;
        c_r[r] = sw[h * NSEQ + row] * 0.125f;  // SCALE = 64^-0.5
        m_r[r] = -1e30f;
        l_r[r] = 0.f;
    }
    const floatx4 fzero = {0.f, 0.f, 0.f, 0.f};
    floatx4 o[4];
#pragma unroll
    for (int dt = 0; dt < 4; ++dt) o[dt] = fzero;

    const int koffK = DMODEL + h * 64;
    const int koffV = 2 * DMODEL + h * 64;

    for (int kb = 0; kb < NSEQ / 64; ++kb) {
        __syncthreads();
        {
            int idx = tid;
#pragma unroll
            for (int it = 0; it < 2; ++it, idx += 256) {
                int key = idx >> 3, dc = (idx & 7) * 8;
                *(bf16x8*)&Kt[key][dc] =
                    *(const bf16x8*)(qkv + (size_t)(kb * 64 + key) * QKVLD + koffK + dc);
            }
            idx = tid;
#pragma unroll
            for (int it = 0; it < 2; ++it, idx += 256) {
                int key = idx >> 3, dc = (idx & 7) * 8;
                bf16x8 v = *(const bf16x8*)(qkv + (size_t)(kb * 64 + key) * QKVLD + koffV + dc);
#pragma unroll
                for (int ii = 0; ii < 8; ++ii) VT[dc + ii][key] = v[ii];
            }
        }
        __syncthreads();

        floatx4 S[4];
#pragma unroll
        for (int ks = 0; ks < 4; ++ks) {
            bf16x8 b0 = *(const bf16x8*)(&Kt[ks * 16 + lr][quad * 8]);
            bf16x8 b1 = *(const bf16x8*)(&Kt[ks * 16 + lr][32 + quad * 8]);
            floatx4 s = fzero;
            s = __builtin_amdgcn_mfma_f32_16x16x32_bf16(qf0, b0, s, 0, 0, 0);
            s = __builtin_amdgcn_mfma_f32_16x16x32_bf16(qf1, b1, s, 0, 0, 0);
            S[ks] = s;
        }

        float P[4][4];
#pragma unroll
        for (int r = 0; r < 4; ++r) {
            float mx = m_r[r];
#pragma unroll
            for (int ks = 0; ks < 4; ++ks) {
                float L = c_r[r] * S[ks][r];
                mx = fmaxf(mx, L);
            }
#pragma unroll
            for (int off = 1; off < 16; off <<= 1)
                mx = fmaxf(mx, __shfl_xor(mx, off, 64));
            float sum = 0.f;
#pragma unroll
            for (int ks = 0; ks < 4; ++ks) {
                float p = __expf(c_r[r] * S[ks][r] - mx);
                P[ks][r] = p;
                sum += p;
            }
#pragma unroll
            for (int off = 1; off < 16; off <<= 1) sum += __shfl_xor(sum, off, 64);
            float alpha = __expf(m_r[r] - mx);
            l_r[r] = l_r[r] * alpha + sum;
            m_r[r] = mx;
#pragma unroll
            for (int dt = 0; dt < 4; ++dt) o[dt][r] *= alpha;
        }

#pragma unroll
        for (int ks = 0; ks < 4; ++ks)
#pragma unroll
            for (int r = 0; r < 4; ++r)
                Pw[wave][quad * 4 + r][ks * 16 + lr] = (bf16_t)P[ks][r];
        __syncthreads();

        bf16x8 pa0 = *(const bf16x8*)(&Pw[wave][lr][quad * 8]);
        bf16x8 pa1 = *(const bf16x8*)(&Pw[wave][lr][32 + quad * 8]);
#pragma unroll
        for (int dt = 0; dt < 4; ++dt) {
            bf16x8 vb0 = *(const bf16x8*)(&VT[dt * 16 + lr][quad * 8]);
            bf16x8 vb1 = *(const bf16x8*)(&VT[dt * 16 + lr][32 + quad * 8]);
            o[dt] = __builtin_amdgcn_mfma_f32_16x16x32_bf16(pa0, vb0, o[dt], 0, 0, 0);
            o[dt] = __builtin_amdgcn_mfma_f32_16x16x32_bf16(pa1, vb1, o[dt], 0, 0, 0);
        }
    }

#pragma unroll
    for (int dt = 0; dt < 4; ++dt)
#pragma unroll
        for (int r = 0; r < 4; ++r) {
            int row = q0 + wave * 16 + quad * 4 + r;
            attn_out[(size_t)row * DMODEL + h * 64 + dt * 16 + lr] =
                (bf16_t)(o[dt][r] / l_r[r]);
        }
}

// ---------------------------------------------------------------------------
extern "C" void kernel_launch(void* const* d_in, const int* in_sizes, int n_in,
                              void* d_out, int out_size, void* d_ws, size_t ws_size,
                              hipStream_t stream) {
    const float* x    = (const float*)d_in[0];
    const float* Wqkv = (const float*)d_in[1];
    const float* W1   = (const float*)d_in[2];
    const float* b1   = (const float*)d_in[3];
    const float* W2   = (const float*)d_in[4];
    const float* b2   = (const float*)d_in[5];
    const float* Wout = (const float*)d_in[6];
    const float* bout = (const float*)d_in[7];
    float* out = (float*)d_out;   // reference returns float32

    char* ws = (char*)d_ws;
    bf16_t* WqkvT = (bf16_t*)(ws);                       // 3072*1024*2 = 6291456
    bf16_t* WoutT = (bf16_t*)(ws + 6291456);             // 1024*1024*2 = 2097152
    bf16_t* qkv   = (bf16_t*)(ws + 8388608);             // 3072*3072*2 = 18874368
    bf16_t* attn  = (bf16_t*)(ws + 27262976);            // 3072*1024*2 = 6291456
    float*  sfull = (float*)(ws + 33554432);             // 16*3072*4
    float*  swp   = (float*)(ws + 33751040);             // 16*3072*4

    // weight transposes + f32->bf16 convert
    transpose_k<<<dim3(NSEQ / 64, DMODEL / 64), 256, 0, stream>>>(Wqkv, WqkvT, DMODEL, NSEQ);
    transpose_k<<<dim3(DMODEL / 64, DMODEL / 64), 256, 0, stream>>>(Wout, WoutT, DMODEL, DMODEL);

    // qkv = x @ Wqkv  -> [3072][3072] bf16  (x is f32, converted in staging)
    gemm_bt<float, bf16_t><<<dim3(NSEQ / 128, NSEQ / 128), 256, 0, stream>>>(
        x, WqkvT, nullptr, qkv, NSEQ, NSEQ, DMODEL);
    // spiky MLP + per-head softmax
    spiky_s<<<dim3(NSEQ / 256, 16), 256, 0, stream>>>(qkv, W1, b1, W2, b2, sfull);
    spiky_softmax<<<16, 256, 0, stream>>>(sfull, swp);

    // flash attention
    attn_kernel<<<dim3(NSEQ / 64, 16), 256, 0, stream>>>(qkv, swp, attn);

    // out = attn @ Wout + bout  -> f32 output
    gemm_bt<bf16_t, float><<<dim3(DMODEL / 128, NSEQ / 128), 256, 0, stream>>>(
        attn, WoutT, bout, out, NSEQ, DMODEL, DMODEL);
}

// Round 5
// 281.873 us; speedup vs baseline: 1.4812x; 1.4812x over previous
//
#include <hip/hip_runtime.h>
#include <hip/hip_bf16.h>
#include <math.h>

typedef __bf16 bf16_t;
typedef __bf16 bf16x2 __attribute__((ext_vector_type(2)));
typedef __bf16 bf16x8 __attribute__((ext_vector_type(8)));
typedef float floatx4 __attribute__((ext_vector_type(4)));

#define NSEQ 3072
#define QKVLD 3072   // row stride of qkv buffer (3*16*64)
#define DMODEL 1024

// load 8 contiguous elements as bf16x8, converting if source is f32
__device__ inline bf16x8 load8(const bf16_t* p) { return *(const bf16x8*)p; }
__device__ inline bf16x8 load8(const float* p) {
    floatx4 a = *(const floatx4*)p;
    floatx4 b = *(const floatx4*)(p + 4);
    bf16x8 r;
    r[0] = (bf16_t)a[0]; r[1] = (bf16_t)a[1]; r[2] = (bf16_t)a[2]; r[3] = (bf16_t)a[3];
    r[4] = (bf16_t)b[0]; r[5] = (bf16_t)b[1]; r[6] = (bf16_t)b[2]; r[7] = (bf16_t)b[3];
    return r;
}

// ---------------------------------------------------------------------------
// x f32 -> bf16, 8 elements per thread.
// ---------------------------------------------------------------------------
__global__ __launch_bounds__(256) void cvt_f32_bf16(const float* __restrict__ in,
                                                    bf16_t* __restrict__ out) {
    int i = (blockIdx.x * 256 + threadIdx.x) * 8;
    *(bf16x8*)(out + i) = load8(in + i);
}

// ---------------------------------------------------------------------------
// Transpose+convert: in[K][N] f32 (row-major) -> out[N][K] bf16.
// grid (N/64, K/64), block 256.
// ---------------------------------------------------------------------------
__global__ __launch_bounds__(256) void transpose_k(const float* __restrict__ in,
                                                   bf16_t* __restrict__ out,
                                                   int K, int N) {
    __shared__ float T[64][65];
    const int n0 = blockIdx.x * 64, k0 = blockIdx.y * 64;
    const int tid = threadIdx.x;
    const int r = tid >> 2, c0 = (tid & 3) * 16;
#pragma unroll
    for (int i = 0; i < 4; ++i) {
        floatx4 v = *(const floatx4*)(in + (size_t)(k0 + r) * N + n0 + c0 + i * 4);
        T[r][c0 + i * 4 + 0] = v[0];
        T[r][c0 + i * 4 + 1] = v[1];
        T[r][c0 + i * 4 + 2] = v[2];
        T[r][c0 + i * 4 + 3] = v[3];
    }
    __syncthreads();
    bf16x8 o0, o1;
#pragma unroll
    for (int i = 0; i < 8; ++i) {
        o0[i] = (bf16_t)T[c0 + i][r];
        o1[i] = (bf16_t)T[c0 + 8 + i][r];
    }
    *(bf16x8*)(out + (size_t)(n0 + r) * K + k0 + c0)     = o0;
    *(bf16x8*)(out + (size_t)(n0 + r) * K + k0 + c0 + 8) = o1;
}

// ---------------------------------------------------------------------------
// GEMM: C[M][N] = A[M][K] @ BT[N][K]^T + bias. 128x128 tile, BK=64, 4 waves.
// ---------------------------------------------------------------------------
template <typename AT, typename CT>
__global__ __launch_bounds__(256) void gemm_bt(const AT* __restrict__ A,
                                               const bf16_t* __restrict__ BT,
                                               const float* __restrict__ bias,
                                               CT* __restrict__ C,
                                               int M, int N, int K) {
    __shared__ __attribute__((aligned(16))) bf16_t As[128][72];
    __shared__ __attribute__((aligned(16))) bf16_t Bs[128][72];
    const int tid = threadIdx.x;
    const int wave = tid >> 6, lane = tid & 63;
    const int lr = lane & 15, quad = lane >> 4;
    const int wr = (wave >> 1) * 64, wc = (wave & 1) * 64;
    const int m0 = blockIdx.y * 128, n0 = blockIdx.x * 128;

    const floatx4 fzero = {0.f, 0.f, 0.f, 0.f};
    floatx4 acc[4][4];
#pragma unroll
    for (int mi = 0; mi < 4; ++mi)
#pragma unroll
        for (int ni = 0; ni < 4; ++ni) acc[mi][ni] = fzero;

    for (int kb = 0; kb < K; kb += 64) {
        __syncthreads();
        int idx = tid;
#pragma unroll
        for (int it = 0; it < 4; ++it, idx += 256) {
            int row = idx >> 3, dc = (idx & 7) * 8;
            *(bf16x8*)&As[row][dc] = load8(A + (size_t)(m0 + row) * K + kb + dc);
            *(bf16x8*)&Bs[row][dc] = load8(BT + (size_t)(n0 + row) * K + kb + dc);
        }
        __syncthreads();
#pragma unroll
        for (int ch = 0; ch < 2; ++ch) {
            bf16x8 af[4], bfr[4];
#pragma unroll
            for (int mi = 0; mi < 4; ++mi)
                af[mi] = *(const bf16x8*)(&As[wr + mi * 16 + lr][ch * 32 + quad * 8]);
#pragma unroll
            for (int ni = 0; ni < 4; ++ni)
                bfr[ni] = *(const bf16x8*)(&Bs[wc + ni * 16 + lr][ch * 32 + quad * 8]);
#pragma unroll
            for (int mi = 0; mi < 4; ++mi)
#pragma unroll
                for (int ni = 0; ni < 4; ++ni)
                    acc[mi][ni] = __builtin_amdgcn_mfma_f32_16x16x32_bf16(af[mi], bfr[ni], acc[mi][ni], 0, 0, 0);
        }
    }

#pragma unroll
    for (int mi = 0; mi < 4; ++mi)
#pragma unroll
        for (int ni = 0; ni < 4; ++ni) {
            int n = n0 + wc + ni * 16 + lr;
            float bv = bias ? bias[n] : 0.f;
#pragma unroll
            for (int r = 0; r < 4; ++r) {
                int m = m0 + wr + mi * 16 + quad * 4 + r;
                C[(size_t)m * N + n] = (CT)(acc[mi][ni][r] + bv);
            }
        }
}

// ---------------------------------------------------------------------------
// Spiky MLP: s[h][j] = sigmoid(relu(k_j @ W1 + b1) @ W2 + b2). grid (12,16).
// ---------------------------------------------------------------------------
__global__ __launch_bounds__(256) void spiky_s(const bf16_t* __restrict__ qkv,
                                               const float* __restrict__ W1,
                                               const float* __restrict__ b1,
                                               const float* __restrict__ W2,
                                               const float* __restrict__ b2,
                                               float* __restrict__ sfull) {
    __shared__ float W1s[64][65];
    __shared__ float W2s[64], b1s[64];
    const int h = blockIdx.y;
    const int tid = threadIdx.x;
    const int j = blockIdx.x * 256 + tid;
    for (int i = tid; i < 4096; i += 256) W1s[i >> 6][i & 63] = W1[i];
    if (tid < 64) { W2s[tid] = W2[tid]; b1s[tid] = b1[tid]; }
    __syncthreads();
    float kv[64];
    const bf16x8* kp8 = (const bf16x8*)(qkv + (size_t)j * QKVLD + DMODEL + h * 64);
#pragma unroll
    for (int c = 0; c < 8; ++c) {
        bf16x8 v = kp8[c];
#pragma unroll
        for (int ii = 0; ii < 8; ++ii) kv[c * 8 + ii] = (float)v[ii];
    }
    float s = b2[0];
    for (int dd = 0; dd < 64; ++dd) {
        float a = b1s[dd];
#pragma unroll
        for (int d = 0; d < 64; ++d) a += kv[d] * W1s[d][dd];
        a = fmaxf(a, 0.f);
        s += a * W2s[dd];
    }
    s = 1.f / (1.f + __expf(-s));
    sfull[h * NSEQ + j] = s;
}

// Per-head softmax over n. grid 16, block 256.
__global__ __launch_bounds__(256) void spiky_softmax(const float* __restrict__ sfull,
                                                     float* __restrict__ sw) {
    const int h = blockIdx.x, tid = threadIdx.x;
    __shared__ float red[256];
    float mx = -1e30f;
    for (int j = tid; j < NSEQ; j += 256) mx = fmaxf(mx, sfull[h * NSEQ + j]);
    red[tid] = mx;
    __syncthreads();
    for (int s = 128; s > 0; s >>= 1) {
        if (tid < s) red[tid] = fmaxf(red[tid], red[tid + s]);
        __syncthreads();
    }
    mx = red[0];
    __syncthreads();
    float sum = 0.f;
    for (int j = tid; j < NSEQ; j += 256) sum += __expf(sfull[h * NSEQ + j] - mx);
    red[tid] = sum;
    __syncthreads();
    for (int s = 128; s > 0; s >>= 1) {
        if (tid < s) red[tid] += red[tid + s];
        __syncthreads();
    }
    float inv = 1.f / red[0];
    for (int j = tid; j < NSEQ; j += 256) sw[h * NSEQ + j] = __expf(sfull[h * NSEQ + j] - mx) * inv;
}

// ---------------------------------------------------------------------------
// Flash attention, S^T formulation.
//   S^T = K·Q^T  (C-layout: row=key-in-block, col=q)  -> P = exp(S^T) in-register
//   O^T = V^T·P^T via key-slot permutation: slot = quad*8 + (ks&1)*4 + r, so
//   P's C-layout registers feed the PV MFMA B-operand directly (no LDS round
//   trip, no barrier). Logits provably tiny (|z| < 0.05) => no max tracking.
// V^T staged with XOR(row-group) bank swizzle: slot s at row-group g lives at
// column s ^ (g<<3); reads use base (s0 ^ (g<<3)) — NOTE: XOR the full 6-bit
// slot including bit 5 (R4 bug: 32 + (s'^g<<3) != (32+s')^(g<<3) for g>=4).
// grid (48, 16), block 256 (4 waves x 16 q-rows). 1 barrier/iter, dbuf K/V.
// ---------------------------------------------------------------------------
__global__ __launch_bounds__(256) void attn_kernel(const bf16_t* __restrict__ qkv,
                                                   const float* __restrict__ sw,
                                                   bf16_t* __restrict__ attn_out) {
    __shared__ __attribute__((aligned(16))) bf16_t Kt[2][64][72];
    __shared__ __attribute__((aligned(16))) bf16_t VT[2][64][72];

    const int h = blockIdx.y;
    const int q0 = blockIdx.x * 64;
    const int tid = threadIdx.x;
    const int wave = tid >> 6, lane = tid & 63;
    const int lr = lane & 15, quad = lane >> 4;

    // Q B-fragment (q-row = wave*16+lr), pre-scaled by c = sw*SCALE
    const int qrow = q0 + wave * 16 + lr;
    const float c = sw[h * NSEQ + qrow] * 0.125f;
    const bf16_t* qptr = qkv + (size_t)qrow * QKVLD + h * 64;
    bf16x8 qraw0 = *(const bf16x8*)(qptr + quad * 8);
    bf16x8 qraw1 = *(const bf16x8*)(qptr + 32 + quad * 8);
    bf16x8 qf0, qf1;
#pragma unroll
    for (int i = 0; i < 8; ++i) {
        qf0[i] = (bf16_t)(c * (float)qraw0[i]);
        qf1[i] = (bf16_t)(c * (float)qraw1[i]);
    }

    // staging thread mapping
    const int kkey = tid >> 3;          // 0..31 (and +32)
    const int kch  = (tid & 7) * 8;     // dim chunk
    const int vp   = tid >> 3;          // key pair index 0..31
    const int va   = tid & 7;           // dim group (rows va*8..va*8+7)
    // key -> permuted slot: k bits [3:2]->slot[4:3], k[4]->slot[2], k[1:0]->slot[1:0]
    const int vk0 = 2 * vp, rem = vk0 & 31;
    const int vslot = (vk0 & 32) | (((rem >> 2) & 3) << 3) | (((rem >> 4) & 1) << 2) | (rem & 3);
    const int vcol = vslot ^ (va << 3);  // XOR bank swizzle by row group

    const int koffK = DMODEL + h * 64;
    const int koffV = 2 * DMODEL + h * 64;

    // prologue: stage tile 0 into buffer 0
    {
        const bf16_t* kbase = qkv + (size_t)kkey * QKVLD;
        *(bf16x8*)&Kt[0][kkey][kch]      = *(const bf16x8*)(kbase + koffK + kch);
        *(bf16x8*)&Kt[0][kkey + 32][kch] = *(const bf16x8*)(kbase + 32 * QKVLD + koffK + kch);
        bf16x8 v0 = *(const bf16x8*)(qkv + (size_t)vk0 * QKVLD + koffV + va * 8);
        bf16x8 v1 = *(const bf16x8*)(qkv + (size_t)(vk0 + 1) * QKVLD + koffV + va * 8);
#pragma unroll
        for (int ii = 0; ii < 8; ++ii) {
            bf16x2 pr; pr[0] = v0[ii]; pr[1] = v1[ii];
            *(bf16x2*)&VT[0][va * 8 + ii][vcol] = pr;
        }
    }
    __syncthreads();

    const floatx4 fzero = {0.f, 0.f, 0.f, 0.f};
    floatx4 o[4];
#pragma unroll
    for (int dt = 0; dt < 4; ++dt) o[dt] = fzero;
    float ls = 0.f;

    const int lrg = lr >> 3;  // V-read row-group low bit

    for (int kb = 0; kb < NSEQ / 64; ++kb) {
        const int cb = kb & 1, nb = cb ^ 1;

        // prefetch next tile into VGPRs (latency overlapped with compute)
        bf16x8 kA0, kA1, vA0, vA1;
        if (kb < NSEQ / 64 - 1) {
            const size_t r0 = (size_t)((kb + 1) * 64);
            kA0 = *(const bf16x8*)(qkv + (r0 + kkey) * QKVLD + koffK + kch);
            kA1 = *(const bf16x8*)(qkv + (r0 + kkey + 32) * QKVLD + koffK + kch);
            vA0 = *(const bf16x8*)(qkv + (r0 + vk0) * QKVLD + koffV + va * 8);
            vA1 = *(const bf16x8*)(qkv + (r0 + vk0 + 1) * QKVLD + koffV + va * 8);
        }

        // S^T = K·Q^T : 64 keys x 16 q per wave, logits pre-scaled via Q
        floatx4 ST[4];
#pragma unroll
        for (int ks = 0; ks < 4; ++ks) {
            bf16x8 ka0 = *(const bf16x8*)(&Kt[cb][ks * 16 + lr][quad * 8]);
            bf16x8 ka1 = *(const bf16x8*)(&Kt[cb][ks * 16 + lr][32 + quad * 8]);
            floatx4 s = fzero;
            s = __builtin_amdgcn_mfma_f32_16x16x32_bf16(ka0, qf0, s, 0, 0, 0);
            s = __builtin_amdgcn_mfma_f32_16x16x32_bf16(ka1, qf1, s, 0, 0, 0);
            ST[ks] = s;
        }

        // P = exp(S^T); pack into B-frag register order (slot = quad*8 + j,
        // j = (ks&1)*4 + r); accumulate row-sum per lane (keys partitioned by quad)
        bf16x8 p0, p1;
#pragma unroll
        for (int j = 0; j < 8; ++j) {
            float e0 = __expf(ST[j >> 2][j & 3]);
            float e1 = __expf(ST[2 + (j >> 2)][j & 3]);
            p0[j] = (bf16_t)e0;
            p1[j] = (bf16_t)e1;
            ls += e0 + e1;
        }

        // O^T += V^T · P^T  (A = permuted V^T tile, B = P registers)
#pragma unroll
        for (int dt = 0; dt < 4; ++dt) {
            const int g3 = (2 * dt + lrg) << 3;                 // row-group << 3
            bf16x8 vb0 = *(const bf16x8*)(&VT[cb][dt * 16 + lr][(quad * 8) ^ g3]);
            bf16x8 vb1 = *(const bf16x8*)(&VT[cb][dt * 16 + lr][(32 + quad * 8) ^ g3]);
            o[dt] = __builtin_amdgcn_mfma_f32_16x16x32_bf16(vb0, p0, o[dt], 0, 0, 0);
            o[dt] = __builtin_amdgcn_mfma_f32_16x16x32_bf16(vb1, p1, o[dt], 0, 0, 0);
        }

        // write prefetched tile into the other buffer
        if (kb < NSEQ / 64 - 1) {
            *(bf16x8*)&Kt[nb][kkey][kch]      = kA0;
            *(bf16x8*)&Kt[nb][kkey + 32][kch] = kA1;
#pragma unroll
            for (int ii = 0; ii < 8; ++ii) {
                bf16x2 pr; pr[0] = vA0[ii]; pr[1] = vA1[ii];
                *(bf16x2*)&VT[nb][va * 8 + ii][vcol] = pr;
            }
        }
        __syncthreads();
    }

    // row sums: lane holds partial over its quad's keys; reduce across quads
    ls += __shfl_xor(ls, 16, 64);
    ls += __shfl_xor(ls, 32, 64);
    const float inv = 1.f / ls;   // for q = lr

    // epilogue: O^T (C-layout d-major) -> LDS transpose -> coalesced store
    bf16_t* ot = (bf16_t*)&Kt[0][0][0] + wave * 16 * 72;  // [16 q][72]
#pragma unroll
    for (int dt = 0; dt < 4; ++dt)
#pragma unroll
        for (int r = 0; r < 4; ++r)
            ot[lr * 72 + dt * 16 + quad * 4 + r] = (bf16_t)(o[dt][r] * inv);
    __syncthreads();
    const int qq = lane >> 2, cg = (lane & 3) * 16;
    bf16x8 r0 = *(const bf16x8*)&ot[qq * 72 + cg];
    bf16x8 r1 = *(const bf16x8*)&ot[qq * 72 + cg + 8];
    size_t orow = (size_t)(q0 + wave * 16 + qq) * DMODEL + h * 64 + cg;
    *(bf16x8*)&attn_out[orow]     = r0;
    *(bf16x8*)&attn_out[orow + 8] = r1;
}

// ---------------------------------------------------------------------------
extern "C" void kernel_launch(void* const* d_in, const int* in_sizes, int n_in,
                              void* d_out, int out_size, void* d_ws, size_t ws_size,
                              hipStream_t stream) {
    const float* x    = (const float*)d_in[0];
    const float* Wqkv = (const float*)d_in[1];
    const float* W1   = (const float*)d_in[2];
    const float* b1   = (const float*)d_in[3];
    const float* W2   = (const float*)d_in[4];
    const float* b2   = (const float*)d_in[5];
    const float* Wout = (const float*)d_in[6];
    const float* bout = (const float*)d_in[7];
    float* out = (float*)d_out;   // reference returns float32

    char* ws = (char*)d_ws;
    bf16_t* WqkvT = (bf16_t*)(ws);                       // 3072*1024*2 = 6291456
    bf16_t* WoutT = (bf16_t*)(ws + 6291456);             // 1024*1024*2 = 2097152
    bf16_t* qkv   = (bf16_t*)(ws + 8388608);             // 3072*3072*2 = 18874368
    bf16_t* attn  = (bf16_t*)(ws + 27262976);            // 3072*1024*2 = 6291456
    float*  sfull = (float*)(ws + 33554432);             // 16*3072*4
    float*  swp   = (float*)(ws + 33751040);             // 16*3072*4
    // xb overlaps attn: xb dead after qkv GEMM, attn written after (stream-ordered)
    bf16_t* xb    = (bf16_t*)(ws + 27262976);            // 3072*1024*2

    cvt_f32_bf16<<<NSEQ * DMODEL / (256 * 8), 256, 0, stream>>>(x, xb);
    transpose_k<<<dim3(NSEQ / 64, DMODEL / 64), 256, 0, stream>>>(Wqkv, WqkvT, DMODEL, NSEQ);
    transpose_k<<<dim3(DMODEL / 64, DMODEL / 64), 256, 0, stream>>>(Wout, WoutT, DMODEL, DMODEL);

    // qkv = x @ Wqkv  -> [3072][3072] bf16
    gemm_bt<bf16_t, bf16_t><<<dim3(NSEQ / 128, NSEQ / 128), 256, 0, stream>>>(
        xb, WqkvT, nullptr, qkv, NSEQ, NSEQ, DMODEL);
    // spiky MLP + per-head softmax
    spiky_s<<<dim3(NSEQ / 256, 16), 256, 0, stream>>>(qkv, W1, b1, W2, b2, sfull);
    spiky_softmax<<<16, 256, 0, stream>>>(sfull, swp);

    // flash attention
    attn_kernel<<<dim3(NSEQ / 64, 16), 256, 0, stream>>>(qkv, swp, attn);

    // out = attn @ Wout + bout  -> f32 output
    gemm_bt<bf16_t, float><<<dim3(DMODEL / 128, NSEQ / 128), 256, 0, stream>>>(
        attn, WoutT, bout, out, NSEQ, DMODEL, DMODEL);
}

// Round 6
// 270.196 us; speedup vs baseline: 1.5452x; 1.0432x over previous
//
#include <hip/hip_runtime.h>
#include <hip/hip_bf16.h>
#include <math.h>

typedef __bf16 bf16_t;
typedef __bf16 bf16x8 __attribute__((ext_vector_type(8)));
typedef float floatx4 __attribute__((ext_vector_type(4)));

#define NSEQ 3072
#define QKVLD 3072
#define DMODEL 1024

__device__ inline bf16x8 load8(const float* p) {
    floatx4 a = *(const floatx4*)p;
    floatx4 b = *(const floatx4*)(p + 4);
    bf16x8 r;
    r[0] = (bf16_t)a[0]; r[1] = (bf16_t)a[1]; r[2] = (bf16_t)a[2]; r[3] = (bf16_t)a[3];
    r[4] = (bf16_t)b[0]; r[5] = (bf16_t)b[1]; r[6] = (bf16_t)b[2]; r[7] = (bf16_t)b[3];
    return r;
}

// async 16B global->LDS (m97 lever). LDS dest = wave-uniform base + lane*16.
__device__ inline void gload16(const bf16_t* g, bf16_t* l) {
    __builtin_amdgcn_global_load_lds(
        (const __attribute__((address_space(1))) unsigned int*)g,
        (__attribute__((address_space(3))) unsigned int*)l, 16, 0, 0);
}

// ---------------------------------------------------------------------------
// prep: blocks [0,1536) cvt x->xb ; [1536,2304) transpose Wqkv ; [2304,2560) Wout
// ---------------------------------------------------------------------------
__global__ __launch_bounds__(256) void prep_kernel(const float* __restrict__ x,
                                                   const float* __restrict__ Wqkv,
                                                   const float* __restrict__ Wout,
                                                   bf16_t* __restrict__ xb,
                                                   bf16_t* __restrict__ WqkvT,
                                                   bf16_t* __restrict__ WoutT) {
    __shared__ float T[64][65];
    const int b = blockIdx.x, tid = threadIdx.x;
    if (b < 1536) {
        int i = b * 2048 + tid * 8;
        *(bf16x8*)(xb + i) = load8(x + i);
        return;
    }
    const float* in; bf16_t* out; int K, N, bx, by;
    if (b < 2304) { int l = b - 1536; bx = l % 48; by = l / 48; in = Wqkv; out = WqkvT; K = 1024; N = 3072; }
    else          { int l = b - 2304; bx = l & 15; by = l >> 4; in = Wout; out = WoutT; K = 1024; N = 1024; }
    const int n0 = bx * 64, k0 = by * 64;
    const int r = tid >> 2, c0 = (tid & 3) * 16;
#pragma unroll
    for (int i = 0; i < 4; ++i) {
        floatx4 v = *(const floatx4*)(in + (size_t)(k0 + r) * N + n0 + c0 + i * 4);
        T[r][c0 + i * 4 + 0] = v[0]; T[r][c0 + i * 4 + 1] = v[1];
        T[r][c0 + i * 4 + 2] = v[2]; T[r][c0 + i * 4 + 3] = v[3];
    }
    __syncthreads();
    bf16x8 o0, o1;
#pragma unroll
    for (int i = 0; i < 8; ++i) { o0[i] = (bf16_t)T[c0 + i][r]; o1[i] = (bf16_t)T[c0 + 8 + i][r]; }
    *(bf16x8*)(out + (size_t)(n0 + r) * K + k0 + c0)     = o0;
    *(bf16x8*)(out + (size_t)(n0 + r) * K + k0 + c0 + 8) = o1;
}

// ---------------------------------------------------------------------------
// GEMM with global_load_lds staging + XOR-chunk swizzle. Unpadded LDS [128][64].
// slot s of row r holds global chunk s^(r&7); read chunk c at slot c^(r&7).
// ---------------------------------------------------------------------------
template <typename CT>
__global__ __launch_bounds__(256) void gemm_bt(const bf16_t* __restrict__ A,
                                               const bf16_t* __restrict__ BT,
                                               const float* __restrict__ bias,
                                               CT* __restrict__ C,
                                               int M, int N, int K) {
    __shared__ __attribute__((aligned(16))) bf16_t As[128 * 64];
    __shared__ __attribute__((aligned(16))) bf16_t Bs[128 * 64];
    const int tid = threadIdx.x;
    const int wave = tid >> 6, lane = tid & 63;
    const int lr = lane & 15, quad = lane >> 4;
    const int wr = (wave >> 1) * 64, wc = (wave & 1) * 64;
    const int m0 = blockIdx.y * 128, n0 = blockIdx.x * 128;
    const int srow = lane >> 3;                 // 0..7
    const int schunk = (lane & 7) ^ srow;       // XOR-permuted global chunk

    const floatx4 fzero = {0.f, 0.f, 0.f, 0.f};
    floatx4 acc[4][4];
#pragma unroll
    for (int mi = 0; mi < 4; ++mi)
#pragma unroll
        for (int ni = 0; ni < 4; ++ni) acc[mi][ni] = fzero;

    for (int kb = 0; kb < K; kb += 64) {
        __syncthreads();
#pragma unroll
        for (int it = 0; it < 4; ++it) {
            const int r0 = (wave * 4 + it) * 8;
            gload16(A + (size_t)(m0 + r0 + srow) * K + kb + schunk * 8, &As[r0 * 64]);
            gload16(BT + (size_t)(n0 + r0 + srow) * K + kb + schunk * 8, &Bs[r0 * 64]);
        }
        __syncthreads();
#pragma unroll
        for (int ch = 0; ch < 2; ++ch) {
            bf16x8 af[4], bfr[4];
#pragma unroll
            for (int mi = 0; mi < 4; ++mi)
                af[mi] = *(const bf16x8*)(&As[(wr + mi * 16 + lr) * 64 + (((ch * 4 + quad) ^ (lr & 7)) * 8)]);
#pragma unroll
            for (int ni = 0; ni < 4; ++ni)
                bfr[ni] = *(const bf16x8*)(&Bs[(wc + ni * 16 + lr) * 64 + (((ch * 4 + quad) ^ (lr & 7)) * 8)]);
#pragma unroll
            for (int mi = 0; mi < 4; ++mi)
#pragma unroll
                for (int ni = 0; ni < 4; ++ni)
                    acc[mi][ni] = __builtin_amdgcn_mfma_f32_16x16x32_bf16(af[mi], bfr[ni], acc[mi][ni], 0, 0, 0);
        }
    }

#pragma unroll
    for (int mi = 0; mi < 4; ++mi)
#pragma unroll
        for (int ni = 0; ni < 4; ++ni) {
            int n = n0 + wc + ni * 16 + lr;
            float bv = bias ? bias[n] : 0.f;
#pragma unroll
            for (int r = 0; r < 4; ++r) {
                int m = m0 + wr + mi * 16 + quad * 4 + r;
                C[(size_t)m * N + n] = (CT)(acc[mi][ni][r] + bv);
            }
        }
}

// ---------------------------------------------------------------------------
// prep2: blocks [0,768) build vtp[h][d][kb*64 + slot] (kappa-permuted V^T);
//        blocks [768,960) spiky MLP -> sfull.
// kappa: slot = key5 | key[3:2]<<3 | key[4]<<2 | key[1:0]; inverse used here.
// ---------------------------------------------------------------------------
__global__ __launch_bounds__(256) void prep2_kernel(const bf16_t* __restrict__ qkv,
                                                    const float* __restrict__ W1,
                                                    const float* __restrict__ b1,
                                                    const float* __restrict__ W2,
                                                    const float* __restrict__ b2,
                                                    bf16_t* __restrict__ vtp,
                                                    float* __restrict__ sfull) {
    __shared__ __attribute__((aligned(16))) bf16_t T[64][72];
    __shared__ float W1s[64][65];
    __shared__ float W2s[64], b1s[64];
    const int b = blockIdx.x, tid = threadIdx.x;
    if (b < 768) {
        const int kb = b % 48, h = b / 48;
        const int key = tid >> 3, ch = (tid & 7) * 8;
        *(bf16x8*)&T[key][ch] =
            *(const bf16x8*)(qkv + (size_t)(kb * 64 + key) * QKVLD + 2 * DMODEL + h * 64 + ch);
        *(bf16x8*)&T[key + 32][ch] =
            *(const bf16x8*)(qkv + (size_t)(kb * 64 + key + 32) * QKVLD + 2 * DMODEL + h * 64 + ch);
        __syncthreads();
        const int d = tid >> 2, sg = (tid & 3) * 16;
        bf16x8 v0, v1;
#pragma unroll
        for (int j = 0; j < 8; ++j) {
            int s0 = sg + j, s1 = sg + 8 + j;
            int k0 = (s0 & 32) | (((s0 >> 3) & 3) << 2) | (((s0 >> 2) & 1) << 4) | (s0 & 3);
            int k1 = (s1 & 32) | (((s1 >> 3) & 3) << 2) | (((s1 >> 2) & 1) << 4) | (s1 & 3);
            v0[j] = T[k0][d]; v1[j] = T[k1][d];
        }
        size_t ob = (size_t)(h * 64 + d) * NSEQ + kb * 64 + sg;
        *(bf16x8*)(vtp + ob)     = v0;
        *(bf16x8*)(vtp + ob + 8) = v1;
    } else {
        const int l = b - 768;
        const int h = l / 12, j = (l % 12) * 256 + tid;
        for (int i = tid; i < 4096; i += 256) W1s[i >> 6][i & 63] = W1[i];
        if (tid < 64) { W2s[tid] = W2[tid]; b1s[tid] = b1[tid]; }
        __syncthreads();
        float kv[64];
        const bf16x8* kp8 = (const bf16x8*)(qkv + (size_t)j * QKVLD + DMODEL + h * 64);
#pragma unroll
        for (int c = 0; c < 8; ++c) {
            bf16x8 v = kp8[c];
#pragma unroll
            for (int ii = 0; ii < 8; ++ii) kv[c * 8 + ii] = (float)v[ii];
        }
        float s = b2[0];
        for (int dd = 0; dd < 64; ++dd) {
            float a = b1s[dd];
#pragma unroll
            for (int d = 0; d < 64; ++d) a += kv[d] * W1s[d][dd];
            a = fmaxf(a, 0.f);
            s += a * W2s[dd];
        }
        sfull[h * NSEQ + j] = 1.f / (1.f + __expf(-s));
    }
}

// ---------------------------------------------------------------------------
// Flash attention: 4 waves; wave = (khalf, qhalf): khalf pair handles K-parity
// khalf tiles, 32 q per wave. Halves merged by adding O and sums (exact: no
// max tracking, logits tiny). Spiky softmax denom computed in-block.
// grid (48, 16), block 256.
// ---------------------------------------------------------------------------
__global__ __launch_bounds__(256) void attn_kernel(const bf16_t* __restrict__ qkv,
                                                   const bf16_t* __restrict__ vtp,
                                                   const float* __restrict__ sfull,
                                                   bf16_t* __restrict__ attn_out) {
    __shared__ __attribute__((aligned(16))) bf16_t Kt[2][64][72];
    __shared__ __attribute__((aligned(16))) bf16_t VT[2][64][72];
    __shared__ float red[256];

    const int h = blockIdx.y;
    const int q0 = blockIdx.x * 64;
    const int tid = threadIdx.x;
    const int wave = tid >> 6, lane = tid & 63;
    const int lr = lane & 15, quad = lane >> 4;
    const int khalf = wave >> 1, qhalf = wave & 1;

    // spiky softmax denominator for head h (max-free: s in [0,1])
    float part = 0.f;
    for (int j = tid; j < NSEQ; j += 256) part += __expf(sfull[h * NSEQ + j]);
    red[tid] = part;
    __syncthreads();
    for (int s = 128; s > 0; s >>= 1) {
        if (tid < s) red[tid] += red[tid + s];
        __syncthreads();
    }
    const float invsum = 1.f / red[0];

    // Q fragments for 2 q-groups, pre-scaled by c = softmax(spiky)*SCALE
    bf16x8 qf[2][2];
#pragma unroll
    for (int qg = 0; qg < 2; ++qg) {
        const int qrow = q0 + qhalf * 32 + qg * 16 + lr;
        const float c = __expf(sfull[h * NSEQ + qrow]) * invsum * 0.125f;
        const bf16_t* qptr = qkv + (size_t)qrow * QKVLD + h * 64;
        bf16x8 a = *(const bf16x8*)(qptr + quad * 8);
        bf16x8 bb = *(const bf16x8*)(qptr + 32 + quad * 8);
#pragma unroll
        for (int i = 0; i < 8; ++i) {
            qf[qg][0][i] = (bf16_t)(c * (float)a[i]);
            qf[qg][1][i] = (bf16_t)(c * (float)bb[i]);
        }
    }

    // staging mapping within the 128-thread khalf-pair
    const int pt = qhalf * 64 + lane;
    const int sr = pt >> 3;          // 0..15 (+16u)
    const int sc = (pt & 7) * 8;

    bf16x8 kR[4], vR[4];
#pragma unroll
    for (int u = 0; u < 4; ++u) {
        const int r = sr + 16 * u;
        kR[u] = *(const bf16x8*)(qkv + (size_t)(khalf * 64 + r) * QKVLD + DMODEL + h * 64 + sc);
        vR[u] = *(const bf16x8*)(vtp + (size_t)(h * 64 + r) * NSEQ + khalf * 64 + sc);
    }

    const floatx4 fzero = {0.f, 0.f, 0.f, 0.f};
    floatx4 o[2][4];
#pragma unroll
    for (int qg = 0; qg < 2; ++qg)
#pragma unroll
        for (int dt = 0; dt < 4; ++dt) o[qg][dt] = fzero;
    float ls[2] = {0.f, 0.f};

    int kb = khalf;
    for (int it = 0; it < 24; ++it) {
        __syncthreads();
#pragma unroll
        for (int u = 0; u < 4; ++u) {
            const int r = sr + 16 * u;
            *(bf16x8*)&Kt[khalf][r][sc] = kR[u];
            *(bf16x8*)&VT[khalf][r][sc] = vR[u];
        }
        __syncthreads();
        if (it < 23) {
            const int kn = kb + 2;
#pragma unroll
            for (int u = 0; u < 4; ++u) {
                const int r = sr + 16 * u;
                kR[u] = *(const bf16x8*)(qkv + (size_t)(kn * 64 + r) * QKVLD + DMODEL + h * 64 + sc);
                vR[u] = *(const bf16x8*)(vtp + (size_t)(h * 64 + r) * NSEQ + kn * 64 + sc);
            }
        }

        // S^T = K.Q^T for 32 q (K-frags shared across both q-groups)
        floatx4 ST[2][4];
#pragma unroll
        for (int ks = 0; ks < 4; ++ks) {
            bf16x8 ka0 = *(const bf16x8*)(&Kt[khalf][ks * 16 + lr][quad * 8]);
            bf16x8 ka1 = *(const bf16x8*)(&Kt[khalf][ks * 16 + lr][32 + quad * 8]);
#pragma unroll
            for (int qg = 0; qg < 2; ++qg) {
                floatx4 s = fzero;
                s = __builtin_amdgcn_mfma_f32_16x16x32_bf16(ka0, qf[qg][0], s, 0, 0, 0);
                s = __builtin_amdgcn_mfma_f32_16x16x32_bf16(ka1, qf[qg][1], s, 0, 0, 0);
                ST[qg][ks] = s;
            }
        }
        // P = exp(S^T), packed directly into PV B-frag order
        bf16x8 p0[2], p1[2];
#pragma unroll
        for (int qg = 0; qg < 2; ++qg)
#pragma unroll
            for (int j = 0; j < 8; ++j) {
                float e0 = __expf(ST[qg][j >> 2][j & 3]);
                float e1 = __expf(ST[qg][2 + (j >> 2)][j & 3]);
                p0[qg][j] = (bf16_t)e0;
                p1[qg][j] = (bf16_t)e1;
                ls[qg] += e0 + e1;
            }
        // O^T += V^T.P^T (V-frags shared across q-groups)
#pragma unroll
        for (int dt = 0; dt < 4; ++dt) {
            bf16x8 vb0 = *(const bf16x8*)(&VT[khalf][dt * 16 + lr][quad * 8]);
            bf16x8 vb1 = *(const bf16x8*)(&VT[khalf][dt * 16 + lr][32 + quad * 8]);
#pragma unroll
            for (int qg = 0; qg < 2; ++qg) {
                o[qg][dt] = __builtin_amdgcn_mfma_f32_16x16x32_bf16(vb0, p0[qg], o[qg][dt], 0, 0, 0);
                o[qg][dt] = __builtin_amdgcn_mfma_f32_16x16x32_bf16(vb1, p1[qg], o[qg][dt], 0, 0, 0);
            }
        }
        kb += 2;
    }

    // reduce ls across quads (keys quad-partitioned within the wave)
#pragma unroll
    for (int qg = 0; qg < 2; ++qg) {
        ls[qg] += __shfl_xor(ls[qg], 16, 64);
        ls[qg] += __shfl_xor(ls[qg], 32, 64);
    }

    // merge khalf halves: khalf=1 spills O + sums to LDS; khalf=0 adds.
    float* obuf  = (float*)&Kt[0][0][0];   // [64 q][66] f32 = 16896 B
    float* lsbuf = obuf + 64 * 66;         // 64 f32 (17152 <= 18432)
    __syncthreads();
    if (khalf == 1) {
#pragma unroll
        for (int qg = 0; qg < 2; ++qg) {
            const int qi = qhalf * 32 + qg * 16 + lr;
#pragma unroll
            for (int dt = 0; dt < 4; ++dt)
#pragma unroll
                for (int r = 0; r < 4; ++r)
                    obuf[qi * 66 + dt * 16 + quad * 4 + r] = o[qg][dt][r];
            if (quad == 0) lsbuf[qi] = ls[qg];
        }
    }
    __syncthreads();
    bf16_t* ot = (bf16_t*)&VT[0][0][0];    // [64 q][72] bf16
    if (khalf == 0) {
#pragma unroll
        for (int qg = 0; qg < 2; ++qg) {
            const int qi = qhalf * 32 + qg * 16 + lr;
            const float inv = 1.f / (ls[qg] + lsbuf[qi]);
#pragma unroll
            for (int dt = 0; dt < 4; ++dt)
#pragma unroll
                for (int r = 0; r < 4; ++r) {
                    float v = (o[qg][dt][r] + obuf[qi * 66 + dt * 16 + quad * 4 + r]) * inv;
                    ot[qi * 72 + dt * 16 + quad * 4 + r] = (bf16_t)v;
                }
        }
    }
    __syncthreads();
    const int row = tid >> 2, cg = (tid & 3) * 16;
    bf16x8 r0 = *(const bf16x8*)&ot[row * 72 + cg];
    bf16x8 r1 = *(const bf16x8*)&ot[row * 72 + cg + 8];
    size_t orow = (size_t)(q0 + row) * DMODEL + h * 64 + cg;
    *(bf16x8*)&attn_out[orow]     = r0;
    *(bf16x8*)&attn_out[orow + 8] = r1;
}

// ---------------------------------------------------------------------------
extern "C" void kernel_launch(void* const* d_in, const int* in_sizes, int n_in,
                              void* d_out, int out_size, void* d_ws, size_t ws_size,
                              hipStream_t stream) {
    const float* x    = (const float*)d_in[0];
    const float* Wqkv = (const float*)d_in[1];
    const float* W1   = (const float*)d_in[2];
    const float* b1   = (const float*)d_in[3];
    const float* W2   = (const float*)d_in[4];
    const float* b2   = (const float*)d_in[5];
    const float* Wout = (const float*)d_in[6];
    const float* bout = (const float*)d_in[7];
    float* out = (float*)d_out;

    char* ws = (char*)d_ws;
    bf16_t* WqkvT = (bf16_t*)(ws);                       // 6291456 B; dead after qkv GEMM
    bf16_t* vtp   = (bf16_t*)(ws);                       // reuses WqkvT region (6291456 B)
    bf16_t* WoutT = (bf16_t*)(ws + 6291456);             // 2097152
    bf16_t* qkv   = (bf16_t*)(ws + 8388608);             // 18874368
    bf16_t* attn  = (bf16_t*)(ws + 27262976);            // 6291456
    bf16_t* xb    = (bf16_t*)(ws + 27262976);            // overlaps attn (xb dead first)
    float*  sfull = (float*)(ws + 33554432);             // 196608

    // 1) cvt x + transpose both weights
    prep_kernel<<<2560, 256, 0, stream>>>(x, Wqkv, Wout, xb, WqkvT, WoutT);
    // 2) qkv = xb @ WqkvT^T
    gemm_bt<bf16_t><<<dim3(24, 24), 256, 0, stream>>>(xb, WqkvT, nullptr, qkv, NSEQ, NSEQ, DMODEL);
    // 3) vtp (kappa-permuted V^T, overwrites WqkvT) + spiky MLP
    prep2_kernel<<<960, 256, 0, stream>>>(qkv, W1, b1, W2, b2, vtp, sfull);
    // 4) attention (spiky softmax folded in)
    attn_kernel<<<dim3(48, 16), 256, 0, stream>>>(qkv, vtp, sfull, attn);
    // 5) out = attn @ WoutT^T + bout
    gemm_bt<float><<<dim3(8, 24), 256, 0, stream>>>(attn, WoutT, bout, out, NSEQ, DMODEL, DMODEL);
}

// Round 7
// 267.659 us; speedup vs baseline: 1.5599x; 1.0095x over previous
//
#include <hip/hip_runtime.h>
#include <hip/hip_bf16.h>
#include <math.h>

typedef __bf16 bf16_t;
typedef __bf16 bf16x8 __attribute__((ext_vector_type(8)));
typedef float floatx4 __attribute__((ext_vector_type(4)));

#define NSEQ 3072
#define QKVLD 3072
#define DMODEL 1024

__device__ inline bf16x8 load8(const float* p) {
    floatx4 a = *(const floatx4*)p;
    floatx4 b = *(const floatx4*)(p + 4);
    bf16x8 r;
    r[0] = (bf16_t)a[0]; r[1] = (bf16_t)a[1]; r[2] = (bf16_t)a[2]; r[3] = (bf16_t)a[3];
    r[4] = (bf16_t)b[0]; r[5] = (bf16_t)b[1]; r[6] = (bf16_t)b[2]; r[7] = (bf16_t)b[3];
    return r;
}

// async 16B global->LDS. LDS dest = wave-uniform base + lane*16.
__device__ inline void gload16(const bf16_t* g, bf16_t* l) {
    __builtin_amdgcn_global_load_lds(
        (const __attribute__((address_space(1))) unsigned int*)g,
        (__attribute__((address_space(3))) unsigned int*)l, 16, 0, 0);
}

// ---------------------------------------------------------------------------
// prep: [0,1536) cvt x->xb ; [1536,2304) transpose Wqkv ; [2304,2560) Wout.
// Block 0 also zeroes hsum[16] (consumed by prep2's atomics, stream-ordered).
// ---------------------------------------------------------------------------
__global__ __launch_bounds__(256) void prep_kernel(const float* __restrict__ x,
                                                   const float* __restrict__ Wqkv,
                                                   const float* __restrict__ Wout,
                                                   bf16_t* __restrict__ xb,
                                                   bf16_t* __restrict__ WqkvT,
                                                   bf16_t* __restrict__ WoutT,
                                                   float* __restrict__ hsum) {
    __shared__ float T[64][65];
    const int b = blockIdx.x, tid = threadIdx.x;
    if (b < 1536) {
        if (b == 0 && tid < 16) hsum[tid] = 0.f;
        int i = b * 2048 + tid * 8;
        *(bf16x8*)(xb + i) = load8(x + i);
        return;
    }
    const float* in; bf16_t* out; int K, N, bx, by;
    if (b < 2304) { int l = b - 1536; bx = l % 48; by = l / 48; in = Wqkv; out = WqkvT; K = 1024; N = 3072; }
    else          { int l = b - 2304; bx = l & 15; by = l >> 4; in = Wout; out = WoutT; K = 1024; N = 1024; }
    const int n0 = bx * 64, k0 = by * 64;
    const int r = tid >> 2, c0 = (tid & 3) * 16;
#pragma unroll
    for (int i = 0; i < 4; ++i) {
        floatx4 v = *(const floatx4*)(in + (size_t)(k0 + r) * N + n0 + c0 + i * 4);
        T[r][c0 + i * 4 + 0] = v[0]; T[r][c0 + i * 4 + 1] = v[1];
        T[r][c0 + i * 4 + 2] = v[2]; T[r][c0 + i * 4 + 3] = v[3];
    }
    __syncthreads();
    bf16x8 o0, o1;
#pragma unroll
    for (int i = 0; i < 8; ++i) { o0[i] = (bf16_t)T[c0 + i][r]; o1[i] = (bf16_t)T[c0 + 8 + i][r]; }
    *(bf16x8*)(out + (size_t)(n0 + r) * K + k0 + c0)     = o0;
    *(bf16x8*)(out + (size_t)(n0 + r) * K + k0 + c0 + 8) = o1;
}

// ---------------------------------------------------------------------------
// GEMM with global_load_lds staging + XOR-chunk swizzle (unchanged from R6).
// ---------------------------------------------------------------------------
template <typename CT>
__global__ __launch_bounds__(256) void gemm_bt(const bf16_t* __restrict__ A,
                                               const bf16_t* __restrict__ BT,
                                               const float* __restrict__ bias,
                                               CT* __restrict__ C,
                                               int M, int N, int K) {
    __shared__ __attribute__((aligned(16))) bf16_t As[128 * 64];
    __shared__ __attribute__((aligned(16))) bf16_t Bs[128 * 64];
    const int tid = threadIdx.x;
    const int wave = tid >> 6, lane = tid & 63;
    const int lr = lane & 15, quad = lane >> 4;
    const int wr = (wave >> 1) * 64, wc = (wave & 1) * 64;
    const int m0 = blockIdx.y * 128, n0 = blockIdx.x * 128;
    const int srow = lane >> 3;
    const int schunk = (lane & 7) ^ srow;

    const floatx4 fzero = {0.f, 0.f, 0.f, 0.f};
    floatx4 acc[4][4];
#pragma unroll
    for (int mi = 0; mi < 4; ++mi)
#pragma unroll
        for (int ni = 0; ni < 4; ++ni) acc[mi][ni] = fzero;

    for (int kb = 0; kb < K; kb += 64) {
        __syncthreads();
#pragma unroll
        for (int it = 0; it < 4; ++it) {
            const int r0 = (wave * 4 + it) * 8;
            gload16(A + (size_t)(m0 + r0 + srow) * K + kb + schunk * 8, &As[r0 * 64]);
            gload16(BT + (size_t)(n0 + r0 + srow) * K + kb + schunk * 8, &Bs[r0 * 64]);
        }
        __syncthreads();
#pragma unroll
        for (int ch = 0; ch < 2; ++ch) {
            bf16x8 af[4], bfr[4];
#pragma unroll
            for (int mi = 0; mi < 4; ++mi)
                af[mi] = *(const bf16x8*)(&As[(wr + mi * 16 + lr) * 64 + (((ch * 4 + quad) ^ (lr & 7)) * 8)]);
#pragma unroll
            for (int ni = 0; ni < 4; ++ni)
                bfr[ni] = *(const bf16x8*)(&Bs[(wc + ni * 16 + lr) * 64 + (((ch * 4 + quad) ^ (lr & 7)) * 8)]);
#pragma unroll
            for (int mi = 0; mi < 4; ++mi)
#pragma unroll
                for (int ni = 0; ni < 4; ++ni)
                    acc[mi][ni] = __builtin_amdgcn_mfma_f32_16x16x32_bf16(af[mi], bfr[ni], acc[mi][ni], 0, 0, 0);
        }
    }

#pragma unroll
    for (int mi = 0; mi < 4; ++mi)
#pragma unroll
        for (int ni = 0; ni < 4; ++ni) {
            int n = n0 + wc + ni * 16 + lr;
            float bv = bias ? bias[n] : 0.f;
#pragma unroll
            for (int r = 0; r < 4; ++r) {
                int m = m0 + wr + mi * 16 + quad * 4 + r;
                C[(size_t)m * N + n] = (CT)(acc[mi][ni][r] + bv);
            }
        }
}

// ---------------------------------------------------------------------------
// prep2: [0,768) build vtp[h][d][kb*64 + slot] (kappa-permuted V^T);
//        [768,960) spiky MLP -> sfull, plus atomicAdd of exp-sum into hsum[h].
// ---------------------------------------------------------------------------
__global__ __launch_bounds__(256) void prep2_kernel(const bf16_t* __restrict__ qkv,
                                                    const float* __restrict__ W1,
                                                    const float* __restrict__ b1,
                                                    const float* __restrict__ W2,
                                                    const float* __restrict__ b2,
                                                    bf16_t* __restrict__ vtp,
                                                    float* __restrict__ sfull,
                                                    float* __restrict__ hsum) {
    __shared__ __attribute__((aligned(16))) bf16_t T[64][72];
    __shared__ float W1s[64][65];
    __shared__ float W2s[64], b1s[64];
    const int b = blockIdx.x, tid = threadIdx.x;
    if (b < 768) {
        const int kb = b % 48, h = b / 48;
        const int key = tid >> 3, ch = (tid & 7) * 8;
        *(bf16x8*)&T[key][ch] =
            *(const bf16x8*)(qkv + (size_t)(kb * 64 + key) * QKVLD + 2 * DMODEL + h * 64 + ch);
        *(bf16x8*)&T[key + 32][ch] =
            *(const bf16x8*)(qkv + (size_t)(kb * 64 + key + 32) * QKVLD + 2 * DMODEL + h * 64 + ch);
        __syncthreads();
        const int d = tid >> 2, sg = (tid & 3) * 16;
        bf16x8 v0, v1;
#pragma unroll
        for (int j = 0; j < 8; ++j) {
            int s0 = sg + j, s1 = sg + 8 + j;
            int k0 = (s0 & 32) | (((s0 >> 3) & 3) << 2) | (((s0 >> 2) & 1) << 4) | (s0 & 3);
            int k1 = (s1 & 32) | (((s1 >> 3) & 3) << 2) | (((s1 >> 2) & 1) << 4) | (s1 & 3);
            v0[j] = T[k0][d]; v1[j] = T[k1][d];
        }
        size_t ob = (size_t)(h * 64 + d) * NSEQ + kb * 64 + sg;
        *(bf16x8*)(vtp + ob)     = v0;
        *(bf16x8*)(vtp + ob + 8) = v1;
    } else {
        const int l = b - 768;
        const int h = l / 12, j = (l % 12) * 256 + tid;
        for (int i = tid; i < 4096; i += 256) W1s[i >> 6][i & 63] = W1[i];
        if (tid < 64) { W2s[tid] = W2[tid]; b1s[tid] = b1[tid]; }
        __syncthreads();
        float kv[64];
        const bf16x8* kp8 = (const bf16x8*)(qkv + (size_t)j * QKVLD + DMODEL + h * 64);
#pragma unroll
        for (int c = 0; c < 8; ++c) {
            bf16x8 v = kp8[c];
#pragma unroll
            for (int ii = 0; ii < 8; ++ii) kv[c * 8 + ii] = (float)v[ii];
        }
        float s = b2[0];
        for (int dd = 0; dd < 64; ++dd) {
            float a = b1s[dd];
#pragma unroll
            for (int d = 0; d < 64; ++d) a += kv[d] * W1s[d][dd];
            a = fmaxf(a, 0.f);
            s += a * W2s[dd];
        }
        s = 1.f / (1.f + __expf(-s));
        sfull[h * NSEQ + j] = s;
        // per-head denominator: wave-reduce exp(s), one atomic per wave
        float e = __expf(s);
#pragma unroll
        for (int off = 1; off < 64; off <<= 1) e += __shfl_xor(e, off, 64);
        if ((tid & 63) == 0) atomicAdd(&hsum[h], e);
    }
}

// ---------------------------------------------------------------------------
// Flash attention (R5 lean shape + vtp + precomputed hsum).
//   S^T = K.Q^T, P = exp(S^T) in-register (logits tiny => no max tracking),
//   O^T = V^T.P^T with kappa-permuted V so P's C-layout regs feed PV directly.
// grid (48,16), block 256 (4 waves x 16 q). dbuf K/V, 1 barrier/iter.
// ---------------------------------------------------------------------------
__global__ __launch_bounds__(256) void attn_kernel(const bf16_t* __restrict__ qkv,
                                                   const bf16_t* __restrict__ vtp,
                                                   const float* __restrict__ sfull,
                                                   const float* __restrict__ hsum,
                                                   bf16_t* __restrict__ attn_out) {
    __shared__ __attribute__((aligned(16))) bf16_t Kt[2][64][72];
    __shared__ __attribute__((aligned(16))) bf16_t VT[2][64][72];

    const int h = blockIdx.y;
    const int q0 = blockIdx.x * 64;
    const int tid = threadIdx.x;
    const int wave = tid >> 6, lane = tid & 63;
    const int lr = lane & 15, quad = lane >> 4;

    // Q B-fragment, pre-scaled by c = softmax(spiky)*SCALE
    const int qrow = q0 + wave * 16 + lr;
    const float c = __expf(sfull[h * NSEQ + qrow]) * (1.f / hsum[h]) * 0.125f;
    const bf16_t* qptr = qkv + (size_t)qrow * QKVLD + h * 64;
    bf16x8 qraw0 = *(const bf16x8*)(qptr + quad * 8);
    bf16x8 qraw1 = *(const bf16x8*)(qptr + 32 + quad * 8);
    bf16x8 qf0, qf1;
#pragma unroll
    for (int i = 0; i < 8; ++i) {
        qf0[i] = (bf16_t)(c * (float)qraw0[i]);
        qf1[i] = (bf16_t)(c * (float)qraw1[i]);
    }

    // staging mapping: b128 per thread, rows kkey & kkey+32
    const int kkey = tid >> 3;
    const int kch  = (tid & 7) * 8;
    const bf16_t* kbase = qkv + DMODEL + h * 64;
    const bf16_t* vbase = vtp + (size_t)(h * 64) * NSEQ;

    // prologue: stage tile 0
    *(bf16x8*)&Kt[0][kkey][kch]      = *(const bf16x8*)(kbase + (size_t)kkey * QKVLD + kch);
    *(bf16x8*)&Kt[0][kkey + 32][kch] = *(const bf16x8*)(kbase + (size_t)(kkey + 32) * QKVLD + kch);
    *(bf16x8*)&VT[0][kkey][kch]      = *(const bf16x8*)(vbase + (size_t)kkey * NSEQ + kch);
    *(bf16x8*)&VT[0][kkey + 32][kch] = *(const bf16x8*)(vbase + (size_t)(kkey + 32) * NSEQ + kch);
    __syncthreads();

    const floatx4 fzero = {0.f, 0.f, 0.f, 0.f};
    floatx4 o[4];
#pragma unroll
    for (int dt = 0; dt < 4; ++dt) o[dt] = fzero;
    float ls = 0.f;

    for (int kb = 0; kb < 48; ++kb) {
        const int cb = kb & 1, nb = cb ^ 1;

        bf16x8 kA0, kA1, vA0, vA1;
        if (kb < 47) {
            const size_t r0 = (size_t)((kb + 1) * 64);
            kA0 = *(const bf16x8*)(kbase + (r0 + kkey) * QKVLD + kch);
            kA1 = *(const bf16x8*)(kbase + (r0 + kkey + 32) * QKVLD + kch);
            vA0 = *(const bf16x8*)(vbase + (size_t)kkey * NSEQ + r0 + kch);
            vA1 = *(const bf16x8*)(vbase + (size_t)(kkey + 32) * NSEQ + r0 + kch);
        }

        // S^T = K.Q^T : 64 keys x 16 q
        floatx4 ST[4];
#pragma unroll
        for (int ks = 0; ks < 4; ++ks) {
            bf16x8 ka0 = *(const bf16x8*)(&Kt[cb][ks * 16 + lr][quad * 8]);
            bf16x8 ka1 = *(const bf16x8*)(&Kt[cb][ks * 16 + lr][32 + quad * 8]);
            floatx4 s = fzero;
            s = __builtin_amdgcn_mfma_f32_16x16x32_bf16(ka0, qf0, s, 0, 0, 0);
            s = __builtin_amdgcn_mfma_f32_16x16x32_bf16(ka1, qf1, s, 0, 0, 0);
            ST[ks] = s;
        }

        // P = exp(S^T) packed straight into PV B-frag order (slot = quad*8+j)
        bf16x8 p0, p1;
#pragma unroll
        for (int j = 0; j < 8; ++j) {
            float e0 = __expf(ST[j >> 2][j & 3]);
            float e1 = __expf(ST[2 + (j >> 2)][j & 3]);
            p0[j] = (bf16_t)e0;
            p1[j] = (bf16_t)e1;
            ls += e0 + e1;
        }

        // O^T += V^T.P^T
#pragma unroll
        for (int dt = 0; dt < 4; ++dt) {
            bf16x8 vb0 = *(const bf16x8*)(&VT[cb][dt * 16 + lr][quad * 8]);
            bf16x8 vb1 = *(const bf16x8*)(&VT[cb][dt * 16 + lr][32 + quad * 8]);
            o[dt] = __builtin_amdgcn_mfma_f32_16x16x32_bf16(vb0, p0, o[dt], 0, 0, 0);
            o[dt] = __builtin_amdgcn_mfma_f32_16x16x32_bf16(vb1, p1, o[dt], 0, 0, 0);
        }

        if (kb < 47) {
            *(bf16x8*)&Kt[nb][kkey][kch]      = kA0;
            *(bf16x8*)&Kt[nb][kkey + 32][kch] = kA1;
            *(bf16x8*)&VT[nb][kkey][kch]      = vA0;
            *(bf16x8*)&VT[nb][kkey + 32][kch] = vA1;
        }
        __syncthreads();
    }

    // ls: keys are quad-partitioned within the wave
    ls += __shfl_xor(ls, 16, 64);
    ls += __shfl_xor(ls, 32, 64);
    const float inv = 1.f / ls;

    // epilogue: O^T (C-layout) -> LDS transpose -> coalesced store
    bf16_t* ot = (bf16_t*)&Kt[0][0][0] + wave * 16 * 72;
#pragma unroll
    for (int dt = 0; dt < 4; ++dt)
#pragma unroll
        for (int r = 0; r < 4; ++r)
            ot[lr * 72 + dt * 16 + quad * 4 + r] = (bf16_t)(o[dt][r] * inv);
    __syncthreads();
    const int qq = lane >> 2, cg = (lane & 3) * 16;
    bf16x8 r0 = *(const bf16x8*)&ot[qq * 72 + cg];
    bf16x8 r1 = *(const bf16x8*)&ot[qq * 72 + cg + 8];
    size_t orow = (size_t)(q0 + wave * 16 + qq) * DMODEL + h * 64 + cg;
    *(bf16x8*)&attn_out[orow]     = r0;
    *(bf16x8*)&attn_out[orow + 8] = r1;
}

// ---------------------------------------------------------------------------
extern "C" void kernel_launch(void* const* d_in, const int* in_sizes, int n_in,
                              void* d_out, int out_size, void* d_ws, size_t ws_size,
                              hipStream_t stream) {
    const float* x    = (const float*)d_in[0];
    const float* Wqkv = (const float*)d_in[1];
    const float* W1   = (const float*)d_in[2];
    const float* b1   = (const float*)d_in[3];
    const float* W2   = (const float*)d_in[4];
    const float* b2   = (const float*)d_in[5];
    const float* Wout = (const float*)d_in[6];
    const float* bout = (const float*)d_in[7];
    float* out = (float*)d_out;

    char* ws = (char*)d_ws;
    bf16_t* WqkvT = (bf16_t*)(ws);                       // 6291456 B; dead after qkv GEMM
    bf16_t* vtp   = (bf16_t*)(ws);                       // reuses WqkvT region
    bf16_t* WoutT = (bf16_t*)(ws + 6291456);             // 2097152
    bf16_t* qkv   = (bf16_t*)(ws + 8388608);             // 18874368
    bf16_t* attn  = (bf16_t*)(ws + 27262976);            // 6291456
    bf16_t* xb    = (bf16_t*)(ws + 27262976);            // overlaps attn (xb dead first)
    float*  sfull = (float*)(ws + 33554432);             // 196608
    float*  hsum  = (float*)(ws + 33751040);             // 64

    prep_kernel<<<2560, 256, 0, stream>>>(x, Wqkv, Wout, xb, WqkvT, WoutT, hsum);
    gemm_bt<bf16_t><<<dim3(24, 24), 256, 0, stream>>>(xb, WqkvT, nullptr, qkv, NSEQ, NSEQ, DMODEL);
    prep2_kernel<<<960, 256, 0, stream>>>(qkv, W1, b1, W2, b2, vtp, sfull, hsum);
    attn_kernel<<<dim3(48, 16), 256, 0, stream>>>(qkv, vtp, sfull, hsum, attn);
    gemm_bt<float><<<dim3(8, 24), 256, 0, stream>>>(attn, WoutT, bout, out, NSEQ, DMODEL, DMODEL);
}

// Round 8
// 194.099 us; speedup vs baseline: 2.1510x; 1.3790x over previous
//
#include <hip/hip_runtime.h>
#include <hip/hip_bf16.h>
#include <math.h>

typedef __bf16 bf16_t;
typedef __bf16 bf16x8 __attribute__((ext_vector_type(8)));
typedef float floatx4 __attribute__((ext_vector_type(4)));

#define NSEQ 3072
#define QKVLD 3072
#define DMODEL 1024

__device__ inline bf16x8 load8(const float* p) {
    floatx4 a = *(const floatx4*)p;
    floatx4 b = *(const floatx4*)(p + 4);
    bf16x8 r;
    r[0] = (bf16_t)a[0]; r[1] = (bf16_t)a[1]; r[2] = (bf16_t)a[2]; r[3] = (bf16_t)a[3];
    r[4] = (bf16_t)b[0]; r[5] = (bf16_t)b[1]; r[6] = (bf16_t)b[2]; r[7] = (bf16_t)b[3];
    return r;
}

// async 16B global->LDS. LDS dest = wave-uniform base + lane*16.
__device__ inline void gload16(const bf16_t* g, bf16_t* l) {
    __builtin_amdgcn_global_load_lds(
        (const __attribute__((address_space(1))) unsigned int*)g,
        (__attribute__((address_space(3))) unsigned int*)l, 16, 0, 0);
}

// ---------------------------------------------------------------------------
// prep: [0,1536) cvt x->xb ; [1536,2304) transpose Wqkv ; [2304,2560) Wout.
// Block 0 zeroes hsum[16].
// ---------------------------------------------------------------------------
__global__ __launch_bounds__(256) void prep_kernel(const float* __restrict__ x,
                                                   const float* __restrict__ Wqkv,
                                                   const float* __restrict__ Wout,
                                                   bf16_t* __restrict__ xb,
                                                   bf16_t* __restrict__ WqkvT,
                                                   bf16_t* __restrict__ WoutT,
                                                   float* __restrict__ hsum) {
    __shared__ float T[64][65];
    const int b = blockIdx.x, tid = threadIdx.x;
    if (b < 1536) {
        if (b == 0 && tid < 16) hsum[tid] = 0.f;
        int i = b * 2048 + tid * 8;
        *(bf16x8*)(xb + i) = load8(x + i);
        return;
    }
    const float* in; bf16_t* out; int K, N, bx, by;
    if (b < 2304) { int l = b - 1536; bx = l % 48; by = l / 48; in = Wqkv; out = WqkvT; K = 1024; N = 3072; }
    else          { int l = b - 2304; bx = l & 15; by = l >> 4; in = Wout; out = WoutT; K = 1024; N = 1024; }
    const int n0 = bx * 64, k0 = by * 64;
    const int r = tid >> 2, c0 = (tid & 3) * 16;
#pragma unroll
    for (int i = 0; i < 4; ++i) {
        floatx4 v = *(const floatx4*)(in + (size_t)(k0 + r) * N + n0 + c0 + i * 4);
        T[r][c0 + i * 4 + 0] = v[0]; T[r][c0 + i * 4 + 1] = v[1];
        T[r][c0 + i * 4 + 2] = v[2]; T[r][c0 + i * 4 + 3] = v[3];
    }
    __syncthreads();
    bf16x8 o0, o1;
#pragma unroll
    for (int i = 0; i < 8; ++i) { o0[i] = (bf16_t)T[c0 + i][r]; o1[i] = (bf16_t)T[c0 + 8 + i][r]; }
    *(bf16x8*)(out + (size_t)(n0 + r) * K + k0 + c0)     = o0;
    *(bf16x8*)(out + (size_t)(n0 + r) * K + k0 + c0 + 8) = o1;
}

// ---------------------------------------------------------------------------
// GEMM with global_load_lds staging + XOR-chunk swizzle (unchanged from R7).
// ---------------------------------------------------------------------------
template <typename CT>
__global__ __launch_bounds__(256) void gemm_bt(const bf16_t* __restrict__ A,
                                               const bf16_t* __restrict__ BT,
                                               const float* __restrict__ bias,
                                               CT* __restrict__ C,
                                               int M, int N, int K) {
    __shared__ __attribute__((aligned(16))) bf16_t As[128 * 64];
    __shared__ __attribute__((aligned(16))) bf16_t Bs[128 * 64];
    const int tid = threadIdx.x;
    const int wave = tid >> 6, lane = tid & 63;
    const int lr = lane & 15, quad = lane >> 4;
    const int wr = (wave >> 1) * 64, wc = (wave & 1) * 64;
    const int m0 = blockIdx.y * 128, n0 = blockIdx.x * 128;
    const int srow = lane >> 3;
    const int schunk = (lane & 7) ^ srow;

    const floatx4 fzero = {0.f, 0.f, 0.f, 0.f};
    floatx4 acc[4][4];
#pragma unroll
    for (int mi = 0; mi < 4; ++mi)
#pragma unroll
        for (int ni = 0; ni < 4; ++ni) acc[mi][ni] = fzero;

    for (int kb = 0; kb < K; kb += 64) {
        __syncthreads();
#pragma unroll
        for (int it = 0; it < 4; ++it) {
            const int r0 = (wave * 4 + it) * 8;
            gload16(A + (size_t)(m0 + r0 + srow) * K + kb + schunk * 8, &As[r0 * 64]);
            gload16(BT + (size_t)(n0 + r0 + srow) * K + kb + schunk * 8, &Bs[r0 * 64]);
        }
        __syncthreads();
#pragma unroll
        for (int ch = 0; ch < 2; ++ch) {
            bf16x8 af[4], bfr[4];
#pragma unroll
            for (int mi = 0; mi < 4; ++mi)
                af[mi] = *(const bf16x8*)(&As[(wr + mi * 16 + lr) * 64 + (((ch * 4 + quad) ^ (lr & 7)) * 8)]);
#pragma unroll
            for (int ni = 0; ni < 4; ++ni)
                bfr[ni] = *(const bf16x8*)(&Bs[(wc + ni * 16 + lr) * 64 + (((ch * 4 + quad) ^ (lr & 7)) * 8)]);
#pragma unroll
            for (int mi = 0; mi < 4; ++mi)
#pragma unroll
                for (int ni = 0; ni < 4; ++ni)
                    acc[mi][ni] = __builtin_amdgcn_mfma_f32_16x16x32_bf16(af[mi], bfr[ni], acc[mi][ni], 0, 0, 0);
        }
    }

#pragma unroll
    for (int mi = 0; mi < 4; ++mi)
#pragma unroll
        for (int ni = 0; ni < 4; ++ni) {
            int n = n0 + wc + ni * 16 + lr;
            float bv = bias ? bias[n] : 0.f;
#pragma unroll
            for (int r = 0; r < 4; ++r) {
                int m = m0 + wr + mi * 16 + quad * 4 + r;
                C[(size_t)m * N + n] = (CT)(acc[mi][ni][r] + bv);
            }
        }
}

// ---------------------------------------------------------------------------
// prep2: [0,192) spiky MLP -> sfull + hsum atomics.
//        [192,384) per (head, 256-key chunk): Mpart = K^T V, Kpart = sum k,
//        Vpart = sum v (MFMA on transposed tiles; C-layout row=d1,col=d2).
// ---------------------------------------------------------------------------
__global__ __launch_bounds__(256) void prep2_kernel(const bf16_t* __restrict__ qkv,
                                                    const float* __restrict__ W1,
                                                    const float* __restrict__ b1,
                                                    const float* __restrict__ W2,
                                                    const float* __restrict__ b2,
                                                    float* __restrict__ sfull,
                                                    float* __restrict__ hsum,
                                                    float* __restrict__ Mpart,
                                                    float* __restrict__ Kpart,
                                                    float* __restrict__ Vpart) {
    __shared__ __attribute__((aligned(16))) bf16_t Kt[64][72];  // [d][j]
    __shared__ __attribute__((aligned(16))) bf16_t Vt[64][72];  // [d][j]
    __shared__ float W1s[64][65];
    __shared__ float W2s[64], b1s[64];
    const int b = blockIdx.x, tid = threadIdx.x;
    if (b < 192) {
        const int h = b / 12, j = (b % 12) * 256 + tid;
        for (int i = tid; i < 4096; i += 256) W1s[i >> 6][i & 63] = W1[i];
        if (tid < 64) { W2s[tid] = W2[tid]; b1s[tid] = b1[tid]; }
        __syncthreads();
        float kv[64];
        const bf16x8* kp8 = (const bf16x8*)(qkv + (size_t)j * QKVLD + DMODEL + h * 64);
#pragma unroll
        for (int c = 0; c < 8; ++c) {
            bf16x8 v = kp8[c];
#pragma unroll
            for (int ii = 0; ii < 8; ++ii) kv[c * 8 + ii] = (float)v[ii];
        }
        float s = b2[0];
        for (int dd = 0; dd < 64; ++dd) {
            float a = b1s[dd];
#pragma unroll
            for (int d = 0; d < 64; ++d) a += kv[d] * W1s[d][dd];
            a = fmaxf(a, 0.f);
            s += a * W2s[dd];
        }
        s = 1.f / (1.f + __expf(-s));
        sfull[h * NSEQ + j] = s;
        float e = __expf(s);
#pragma unroll
        for (int off = 1; off < 64; off <<= 1) e += __shfl_xor(e, off, 64);
        if ((tid & 63) == 0) atomicAdd(&hsum[h], e);
    } else {
        const int l = b - 192;
        const int h = l / 12, c = l % 12;
        const int wave = tid >> 6, lane = tid & 63;
        const int lr = lane & 15, quad = lane >> 4;
        const int jj = tid >> 3, ch = (tid & 7) * 8;
        const floatx4 fzero = {0.f, 0.f, 0.f, 0.f};
        floatx4 macc[4];
#pragma unroll
        for (int ni = 0; ni < 4; ++ni) macc[ni] = fzero;
        float ksum = 0.f, vsum = 0.f;

        for (int st = 0; st < 4; ++st) {
            const size_t row0 = (size_t)(c * 256 + st * 64);
            bf16x8 k0 = *(const bf16x8*)(qkv + (row0 + jj) * QKVLD + DMODEL + h * 64 + ch);
            bf16x8 k1 = *(const bf16x8*)(qkv + (row0 + jj + 32) * QKVLD + DMODEL + h * 64 + ch);
            bf16x8 v0 = *(const bf16x8*)(qkv + (row0 + jj) * QKVLD + 2 * DMODEL + h * 64 + ch);
            bf16x8 v1 = *(const bf16x8*)(qkv + (row0 + jj + 32) * QKVLD + 2 * DMODEL + h * 64 + ch);
            __syncthreads();   // prior-iter reads done before overwrite
#pragma unroll
            for (int ii = 0; ii < 8; ++ii) {
                Kt[ch + ii][jj] = k0[ii]; Kt[ch + ii][jj + 32] = k1[ii];
                Vt[ch + ii][jj] = v0[ii]; Vt[ch + ii][jj + 32] = v1[ii];
            }
            __syncthreads();
            bf16x8 a0 = *(const bf16x8*)(&Kt[wave * 16 + lr][quad * 8]);
            bf16x8 a1 = *(const bf16x8*)(&Kt[wave * 16 + lr][32 + quad * 8]);
#pragma unroll
            for (int ni = 0; ni < 4; ++ni) {
                bf16x8 b0 = *(const bf16x8*)(&Vt[ni * 16 + lr][quad * 8]);
                bf16x8 b1f = *(const bf16x8*)(&Vt[ni * 16 + lr][32 + quad * 8]);
                macc[ni] = __builtin_amdgcn_mfma_f32_16x16x32_bf16(a0, b0, macc[ni], 0, 0, 0);
                macc[ni] = __builtin_amdgcn_mfma_f32_16x16x32_bf16(a1, b1f, macc[ni], 0, 0, 0);
            }
            if (tid < 64) {
#pragma unroll
                for (int cc = 0; cc < 8; ++cc) {
                    bf16x8 kk = *(const bf16x8*)(&Kt[tid][cc * 8]);
#pragma unroll
                    for (int ii = 0; ii < 8; ++ii) ksum += (float)kk[ii];
                }
            } else if (tid < 128) {
                const int d = tid - 64;
#pragma unroll
                for (int cc = 0; cc < 8; ++cc) {
                    bf16x8 vv = *(const bf16x8*)(&Vt[d][cc * 8]);
#pragma unroll
                    for (int ii = 0; ii < 8; ++ii) vsum += (float)vv[ii];
                }
            }
        }
        const size_t mb = (size_t)(h * 12 + c) * 4096;
#pragma unroll
        for (int ni = 0; ni < 4; ++ni)
#pragma unroll
            for (int r = 0; r < 4; ++r)
                Mpart[mb + (size_t)(wave * 16 + quad * 4 + r) * 64 + ni * 16 + lr] = macc[ni][r];
        if (tid < 64) Kpart[(h * 12 + c) * 64 + tid] = ksum;
        else if (tid < 128) Vpart[(h * 12 + c) * 64 + (tid - 64)] = vsum;
    }
}

// ---------------------------------------------------------------------------
// mreduce: per head, sum the 12 M/Ksum/Vsum partials.
// Mt[h][e][d] (bf16, 80 rows): e<64 -> M[d][e]; e==64 -> Ksum[d]; e>64 -> 0.
// ---------------------------------------------------------------------------
__global__ __launch_bounds__(256) void mreduce_kernel(const float* __restrict__ Mpart,
                                                      const float* __restrict__ Kpart,
                                                      const float* __restrict__ Vpart,
                                                      bf16_t* __restrict__ Mt,
                                                      float* __restrict__ Vsumf) {
    const int h = blockIdx.x, tid = threadIdx.x;
    for (int base = 0; base < 4096; base += 256) {
        const int idx = base + tid;
        const int d1 = idx >> 6, d2 = idx & 63;
        float a = 0.f;
#pragma unroll
        for (int c = 0; c < 12; ++c) a += Mpart[(size_t)(h * 12 + c) * 4096 + idx];
        Mt[((size_t)h * 80 + d2) * 64 + d1] = (bf16_t)a;  // transpose: row=e, col=d
    }
    if (tid < 64) {
        float ka = 0.f, va = 0.f;
#pragma unroll
        for (int c = 0; c < 12; ++c) {
            ka += Kpart[(h * 12 + c) * 64 + tid];
            va += Vpart[(h * 12 + c) * 64 + tid];
        }
        Mt[((size_t)h * 80 + 64) * 64 + tid] = (bf16_t)ka;
        Vsumf[h * 64 + tid] = va;
    }
    for (int i = tid; i < 15 * 64; i += 256)
        Mt[((size_t)h * 80 + 65) * 64 + i] = (bf16_t)0.f;
}

// ---------------------------------------------------------------------------
// attnlite: out_q = (Vsum + q'^T M) / (n + q'.Ksum), q' = c_q * q,
// c_q = e^{s_q}/hsum * SCALE. One MFMA GEMM [64q x 80e] per block.
// grid (48, 16), block 256 (4 waves x 16 q).
// ---------------------------------------------------------------------------
__global__ __launch_bounds__(256) void attnlite_kernel(const bf16_t* __restrict__ qkv,
                                                       const bf16_t* __restrict__ Mt,
                                                       const float* __restrict__ Vsumf,
                                                       const float* __restrict__ sfull,
                                                       const float* __restrict__ hsum,
                                                       bf16_t* __restrict__ attn_out) {
    __shared__ __attribute__((aligned(16))) bf16_t Mts[80][72];
    __shared__ __attribute__((aligned(16))) bf16_t ot[64][72];
    __shared__ float sVs[64];
    __shared__ float sden[64];

    const int h = blockIdx.y;
    const int q0 = blockIdx.x * 64;
    const int tid = threadIdx.x;
    const int wave = tid >> 6, lane = tid & 63;
    const int lr = lane & 15, quad = lane >> 4;

    // stage Mt (80 rows x 64 d) and Vsum
    for (int i = tid; i < 640; i += 256) {
        const int row = i >> 3, ch = (i & 7) * 8;
        *(bf16x8*)&Mts[row][ch] = *(const bf16x8*)(Mt + ((size_t)h * 80 + row) * 64 + ch);
    }
    if (tid < 64) sVs[tid] = Vsumf[h * 64 + tid];

    // q' fragment (a-operand: lane lr = q-row, quad = d-chunk)
    const int qrow = q0 + wave * 16 + lr;
    const float c = __expf(sfull[h * NSEQ + qrow]) * (0.125f / hsum[h]);
    const bf16_t* qptr = qkv + (size_t)qrow * QKVLD + h * 64;
    bf16x8 qraw0 = *(const bf16x8*)(qptr + quad * 8);
    bf16x8 qraw1 = *(const bf16x8*)(qptr + 32 + quad * 8);
    bf16x8 qf0, qf1;
#pragma unroll
    for (int i = 0; i < 8; ++i) {
        qf0[i] = (bf16_t)(c * (float)qraw0[i]);
        qf1[i] = (bf16_t)(c * (float)qraw1[i]);
    }
    __syncthreads();

    const floatx4 fzero = {0.f, 0.f, 0.f, 0.f};
    floatx4 acc[5];
#pragma unroll
    for (int ni = 0; ni < 5; ++ni) acc[ni] = fzero;
#pragma unroll
    for (int ni = 0; ni < 5; ++ni) {
        bf16x8 b0 = *(const bf16x8*)(&Mts[ni * 16 + lr][quad * 8]);
        bf16x8 b1 = *(const bf16x8*)(&Mts[ni * 16 + lr][32 + quad * 8]);
        acc[ni] = __builtin_amdgcn_mfma_f32_16x16x32_bf16(qf0, b0, acc[ni], 0, 0, 0);
        acc[ni] = __builtin_amdgcn_mfma_f32_16x16x32_bf16(qf1, b1, acc[ni], 0, 0, 0);
    }

    // denominator: col e=64 lives at lr==0 of frag 4
    if (lr == 0) {
#pragma unroll
        for (int r = 0; r < 4; ++r) sden[wave * 16 + quad * 4 + r] = acc[4][r];
    }
    __syncthreads();
    float dd[4];
#pragma unroll
    for (int r = 0; r < 4; ++r) dd[r] = (float)NSEQ + sden[wave * 16 + quad * 4 + r];

    // out rows (C-layout: row q = quad*4+r, col e = ni*16+lr) -> LDS -> store
#pragma unroll
    for (int ni = 0; ni < 4; ++ni)
#pragma unroll
        for (int r = 0; r < 4; ++r)
            ot[wave * 16 + quad * 4 + r][ni * 16 + lr] =
                (bf16_t)((sVs[ni * 16 + lr] + acc[ni][r]) / dd[r]);
    __syncthreads();
    const int row = tid >> 2, cg = (tid & 3) * 16;
    bf16x8 r0 = *(const bf16x8*)&ot[row][cg];
    bf16x8 r1 = *(const bf16x8*)&ot[row][cg + 8];
    size_t orow = (size_t)(q0 + row) * DMODEL + h * 64 + cg;
    *(bf16x8*)&attn_out[orow]     = r0;
    *(bf16x8*)&attn_out[orow + 8] = r1;
}

// ---------------------------------------------------------------------------
extern "C" void kernel_launch(void* const* d_in, const int* in_sizes, int n_in,
                              void* d_out, int out_size, void* d_ws, size_t ws_size,
                              hipStream_t stream) {
    const float* x    = (const float*)d_in[0];
    const float* Wqkv = (const float*)d_in[1];
    const float* W1   = (const float*)d_in[2];
    const float* b1   = (const float*)d_in[3];
    const float* W2   = (const float*)d_in[4];
    const float* b2   = (const float*)d_in[5];
    const float* Wout = (const float*)d_in[6];
    const float* bout = (const float*)d_in[7];
    float* out = (float*)d_out;

    char* ws = (char*)d_ws;
    bf16_t* WqkvT = (bf16_t*)(ws);                 // 6291456
    bf16_t* WoutT = (bf16_t*)(ws + 6291456);       // 2097152
    bf16_t* qkv   = (bf16_t*)(ws + 8388608);       // 18874368
    // region [27262976, 33554432): xb (dead after gemm1) -> M partials
    // (dead after mreduce) -> attn (written by attnlite)
    bf16_t* attn  = (bf16_t*)(ws + 27262976);
    bf16_t* xb    = (bf16_t*)(ws + 27262976);
    float*  Mpart = (float*)(ws + 27262976);       // 3145728
    float*  Kpart = (float*)(ws + 30408704);       // 196608
    float*  Vpart = (float*)(ws + 30605312);       // 196608 -> 30801920
    float*  sfull = (float*)(ws + 33554432);       // 196608
    float*  hsum  = (float*)(ws + 33751040);       // 64
    bf16_t* Mt    = (bf16_t*)(ws + 33751104);      // 163840
    float*  Vsumf = (float*)(ws + 33914944);       // 4096 -> 33919040

    prep_kernel<<<2560, 256, 0, stream>>>(x, Wqkv, Wout, xb, WqkvT, WoutT, hsum);
    gemm_bt<bf16_t><<<dim3(24, 24), 256, 0, stream>>>(xb, WqkvT, nullptr, qkv, NSEQ, NSEQ, DMODEL);
    prep2_kernel<<<384, 256, 0, stream>>>(qkv, W1, b1, W2, b2, sfull, hsum, Mpart, Kpart, Vpart);
    mreduce_kernel<<<16, 256, 0, stream>>>(Mpart, Kpart, Vpart, Mt, Vsumf);
    attnlite_kernel<<<dim3(48, 16), 256, 0, stream>>>(qkv, Mt, Vsumf, sfull, hsum, attn);
    gemm_bt<float><<<dim3(8, 24), 256, 0, stream>>>(attn, WoutT, bout, out, NSEQ, DMODEL, DMODEL);
}